// Round 14
// baseline (1225.438 us; speedup 1.0000x reference)
//
#include <hip/hip_runtime.h>

#define NC 100352       // N*C = 196*512
typedef unsigned long long ull;

// ---------------------------------------------------------------------------
// QKV GEMM: round-4 body (validated absmax 0.0): 256x128 tile, BK=16,
// 256 threads, 16x8 microtile, double-buffered LDS (1 barrier/BK).
// NEW: amdgpu_waves_per_eu(2,2) — pins occupancy at 2 waves/EU so the
// allocator has no incentive to clamp VGPRs at 128-136 (the failure mode of
// rounds 4/6/9/10; needs ~200, gets 256 budget at 2 waves).
// LDS math: 6 b128 per 256 VALU-cy per wave-k -> 4x72/256 = 1.125 -> 89% cap.
// k-ascending sequential fmaf per output -> bit-identical.
// ---------------------------------------------------------------------------
template <int NMAT, bool BIAS>
__global__ __launch_bounds__(256)
__attribute__((amdgpu_waves_per_eu(2, 2)))
void gemm_wpe(
    const float* __restrict__ A,
    const float* __restrict__ W0, const float* __restrict__ W1,
    const float* __restrict__ W2, const float* __restrict__ bias,
    float* __restrict__ C0, float* __restrict__ C1, float* __restrict__ C2)
{
    __shared__ float As[2][16][260];   // [buf][k][row 0..255]
    __shared__ float Bs[2][16][132];   // [buf][k][col 0..127]

    const int chunk = (NMAT * 392) >> 3;
    const int w = ((int)blockIdx.x & 7) * chunk + ((int)blockIdx.x >> 3);
    const int mb = w / (4 * NMAT);
    const int rem = w - mb * (4 * NMAT);
    const int br = rem >> 2;
    const int cb = rem & 3;

    const float* Wb = (NMAT == 1 || br == 0) ? W0 : (br == 1 ? W1 : W2);
    float* Cb = (NMAT == 1 || br == 0) ? C0 : (br == 1 ? C1 : C2);

    const int tid = threadIdx.x;
    const int q   = (tid & 3) << 2;    // k offset for staging float4
    const int sr  = tid >> 2;          // 0..63 staging row base
    const int rg4 = (tid >> 4) << 2;   // compute row base (0..60)
    const int cg4 = (tid & 15) << 2;   // compute col base (0..60)

    const float* Ap = A  + (size_t)(mb * 256 + sr) * 512 + q;
    const float* Bp = Wb + (size_t)(cb * 128 + sr) * 512 + q;

    float acc[16][8] = {};
    float4 a4[4], b4[2];

    auto LOAD = [&](int k0) {
#pragma unroll
        for (int s = 0; s < 4; ++s)
            a4[s] = *(const float4*)(Ap + (size_t)s * 64 * 512 + k0);
#pragma unroll
        for (int s = 0; s < 2; ++s)
            b4[s] = *(const float4*)(Bp + (size_t)s * 64 * 512 + k0);
    };
    auto STORE = [&](int buf) {
#pragma unroll
        for (int s = 0; s < 4; ++s) {
            As[buf][q + 0][sr + s * 64] = a4[s].x;
            As[buf][q + 1][sr + s * 64] = a4[s].y;
            As[buf][q + 2][sr + s * 64] = a4[s].z;
            As[buf][q + 3][sr + s * 64] = a4[s].w;
        }
#pragma unroll
        for (int s = 0; s < 2; ++s) {
            Bs[buf][q + 0][sr + s * 64] = b4[s].x;
            Bs[buf][q + 1][sr + s * 64] = b4[s].y;
            Bs[buf][q + 2][sr + s * 64] = b4[s].z;
            Bs[buf][q + 3][sr + s * 64] = b4[s].w;
        }
    };
    auto COMP = [&](int buf) {
#pragma unroll
        for (int k = 0; k < 16; ++k) {
            float av[16], bv[8];
#pragma unroll
            for (int s = 0; s < 4; ++s)
                *(float4*)&av[s * 4] = *(const float4*)&As[buf][k][rg4 + s * 64];
#pragma unroll
            for (int s = 0; s < 2; ++s)
                *(float4*)&bv[s * 4] = *(const float4*)&Bs[buf][k][cg4 + s * 64];
#pragma unroll
            for (int i = 0; i < 16; ++i)
#pragma unroll
                for (int j = 0; j < 8; ++j)
                    acc[i][j] = fmaf(av[i], bv[j], acc[i][j]);
        }
    };

    LOAD(0);
    STORE(0);
    __syncthreads();
    int cur = 0;
    for (int k0 = 0; k0 < 512; k0 += 16) {
        if (k0 + 16 < 512) {
            LOAD(k0 + 16);
            COMP(cur);
            STORE(cur ^ 1);
        } else {
            COMP(cur);
        }
        __syncthreads();
        cur ^= 1;
    }

#pragma unroll
    for (int s = 0; s < 4; ++s)
#pragma unroll
        for (int i = 0; i < 4; ++i) {
            const int row = mb * 256 + rg4 + i + s * 64;
#pragma unroll
            for (int half = 0; half < 2; ++half) {
                const int col = cb * 128 + cg4 + half * 64;
                float4 o;
                o.x = acc[s * 4 + i][half * 4 + 0];
                o.y = acc[s * 4 + i][half * 4 + 1];
                o.z = acc[s * 4 + i][half * 4 + 2];
                o.w = acc[s * 4 + i][half * 4 + 3];
                if (BIAS) {
                    o.x += bias[col + 0]; o.y += bias[col + 1];
                    o.z += bias[col + 2]; o.w += bias[col + 3];
                }
                *(float4*)&Cb[(size_t)row * 512 + col] = o;
            }
        }
}

// ---------------------------------------------------------------------------
// proj GEMM with bitmask A (validated rounds 12/13): 64x128 tile, 1568 blocks.
// ---------------------------------------------------------------------------
__global__ __launch_bounds__(256) void gemm_mask(
    const uint* __restrict__ Am,
    const float* __restrict__ W, const float* __restrict__ bias,
    float* __restrict__ C)
{
    __shared__ float Bs[16][132];

    const int w = ((int)blockIdx.x & 7) * 196 + ((int)blockIdx.x >> 3);
    const int rp = w >> 2;            // 0..391 (64-row panels)
    const int cb = w & 3;

    const int tid = threadIdx.x;
    const int r0 = tid >> 2;
    const int kq = (tid & 3) << 2;
    const int rg = (tid >> 4) << 2;   // 0..60 : 4 rows of 64
    const int cg = (tid & 15) << 2;   // 0..60 : cols cg / cg+64

    const float* B0 = W + (size_t)(cb * 128 + r0) * 512 + kq;
    const float* B1 = B0 + (size_t)64 * 512;

    const uint* mp[4];
#pragma unroll
    for (int i = 0; i < 4; ++i) {
        const int row = rp * 64 + rg + i;
        const int tb = row / 196;
        const int n = row - tb * 196;
        mp[i] = Am + (size_t)tb * 3136 + n * 16;
    }

    float acc[4][8] = {};

    for (int k0 = 0; k0 < 512; k0 += 16) {
        const float4 b0 = *(const float4*)(B0 + k0);
        const float4 b1 = *(const float4*)(B1 + k0);
        uint wv[4];
        const int wi = k0 >> 5;
        const int sh = k0 & 16;
#pragma unroll
        for (int m = 0; m < 4; ++m) wv[m] = mp[m][wi] >> sh;  // low 16 bits
        __syncthreads();
        Bs[kq + 0][r0] = b0.x; Bs[kq + 1][r0] = b0.y;
        Bs[kq + 2][r0] = b0.z; Bs[kq + 3][r0] = b0.w;
        Bs[kq + 0][r0 + 64] = b1.x; Bs[kq + 1][r0 + 64] = b1.y;
        Bs[kq + 2][r0 + 64] = b1.z; Bs[kq + 3][r0 + 64] = b1.w;
        __syncthreads();
#pragma unroll
        for (int k = 0; k < 16; ++k) {
            float bv[8], av[4];
            *(float4*)&bv[0] = *(const float4*)&Bs[k][cg];
            *(float4*)&bv[4] = *(const float4*)&Bs[k][cg + 64];
#pragma unroll
            for (int m = 0; m < 4; ++m)
                av[m] = ((wv[m] >> k) & 1u) ? 1.0f : 0.0f;
#pragma unroll
            for (int i = 0; i < 4; ++i)
#pragma unroll
                for (int j = 0; j < 8; ++j)
                    acc[i][j] = fmaf(av[i], bv[j], acc[i][j]);
        }
    }

#pragma unroll
    for (int i = 0; i < 4; ++i) {
        const int row = rp * 64 + rg + i;
#pragma unroll
        for (int jh = 0; jh < 2; ++jh) {
            const int col = cb * 128 + cg + jh * 64;
            float4 o;
            o.x = acc[i][jh * 4 + 0] + bias[col + 0];
            o.y = acc[i][jh * 4 + 1] + bias[col + 1];
            o.z = acc[i][jh * 4 + 2] + bias[col + 2];
            o.w = acc[i][jh * 4 + 3] + bias[col + 3];
            *(float4*)&C[(size_t)row * 512 + col] = o;
        }
    }
}

// ---------------------------------------------------------------------------
// LIF over 128 steps for Q/K/V, emitting bitmasks (4-step load MLP).
// ---------------------------------------------------------------------------
__global__ __launch_bounds__(256) void lif_mask3(
    const float* __restrict__ U0, const float* __restrict__ U1,
    const float* __restrict__ U2,
    const float* __restrict__ wq, const float* __restrict__ wk,
    const float* __restrict__ wv, ull* __restrict__ M)
{
    const int br = blockIdx.x / 392;
    const int blk = blockIdx.x - br * 392;
    const int i = blk * 256 + threadIdx.x;
    const float* U = (br == 0) ? U0 : (br == 1 ? U1 : U2);
    const float wv_ = (br == 0) ? wq[0] : (br == 1 ? wk[0] : wv[0]);
    const float sg = 1.0f / (1.0f + expf(-wv_));
    const bool l0 = (threadIdx.x & 63) == 0;
    ull* Mw = M + (size_t)br * 200704 + ((i >> 6) & 7) * 196 + (i >> 9);
    float v = 0.0f;
    for (int t0 = 0; t0 < 128; t0 += 4) {
        float x[4];
#pragma unroll
        for (int j = 0; j < 4; ++j) x[j] = U[(size_t)(t0 + j) * NC + i];
#pragma unroll
        for (int j = 0; j < 4; ++j) {
            const float h = __fadd_rn(v, __fmul_rn(__fsub_rn(x[j], v), sg));
            const bool sp = (h >= 1.0f);
            const ull m = __ballot(sp);
            if (l0) Mw[(size_t)(t0 + j) * 1568] = m;
            v = sp ? 0.0f : h;
        }
    }
}

// ---------------------------------------------------------------------------
// proj LIF: float spikes out (4-step load MLP).
// ---------------------------------------------------------------------------
__global__ __launch_bounds__(256) void lif_out(const float* __restrict__ U,
                                               const float* __restrict__ wp,
                                               float* __restrict__ out)
{
    const int i = blockIdx.x * 256 + threadIdx.x;
    const float sg = 1.0f / (1.0f + expf(-wp[0]));
    float v = 0.0f;
    for (int t0 = 0; t0 < 128; t0 += 4) {
        float x[4];
#pragma unroll
        for (int j = 0; j < 4; ++j) x[j] = U[(size_t)(t0 + j) * NC + i];
#pragma unroll
        for (int j = 0; j < 4; ++j) {
            const float h = __fadd_rn(v, __fmul_rn(__fsub_rn(x[j], v), sg));
            const bool sp = (h >= 1.0f);
            out[(size_t)(t0 + j) * NC + i] = sp ? 1.0f : 0.0f;
            v = sp ? 0.0f : h;
        }
    }
}

// ---------------------------------------------------------------------------
// Fused attention + attn_lif, 1024 threads (validated round 13).
// ---------------------------------------------------------------------------
__global__ __launch_bounds__(1024) void attn_fused(const ull* __restrict__ Qm,
                                                   const ull* __restrict__ Km,
                                                   const ull* __restrict__ Vm,
                                                   const float* __restrict__ wa,
                                                   uint* __restrict__ Ym)
{
    const int b = blockIdx.x >> 3;
    const int h = blockIdx.x & 7;
    const int tid = threadIdx.x;
    const int w = tid >> 6;          // 0..15
    const int lane = tid & 63;

    __shared__ ull qrow[256], krow[256], vrow[256];
    __shared__ uint kcol32[64][4][2], vcol32[64][4][2];
    __shared__ ushort G[64][64];
    __shared__ float vstate[196][64];
    __shared__ ull sbm[208];

    const float sg = 1.0f / (1.0f + expf(-wa[0]));

    for (int t = 0; t < 4; ++t) {
        const int tb = t * 32 + b;
        const size_t mb = (size_t)tb * 1568 + (size_t)h * 196;
        if (tid < 196) {
            qrow[tid] = Qm[mb + tid];
            krow[tid] = Km[mb + tid];
            vrow[tid] = Vm[mb + tid];
        } else if (tid < 256) {
            qrow[tid] = 0; krow[tid] = 0; vrow[tid] = 0;
        }
        __syncthreads();

        if (w < 8) {  // transpose: wave w -> (j = w>>1, half = w&1)
            const int j = w >> 1, half = w & 1;
            const int base = j * 64 + half * 32;
            uint kc = 0, vc = 0;
#pragma unroll 8
            for (int m = 0; m < 32; ++m) {
                kc |= (uint)((krow[base + m] >> lane) & 1ull) << m;
                vc |= (uint)((vrow[base + m] >> lane) & 1ull) << m;
            }
            kcol32[lane][j][half] = kc; vcol32[lane][j][half] = vc;
        }
        __syncthreads();

        for (int p = tid; p < 4096; p += 1024) {
            const int d1 = p >> 6, d2 = p & 63;
            int g = 0;
#pragma unroll
            for (int j = 0; j < 4; ++j)
                g += __popc(kcol32[d1][j][0] & vcol32[d2][j][0]) +
                     __popc(kcol32[d1][j][1] & vcol32[d2][j][1]);
            G[d1][d2] = (ushort)g;
        }
        __syncthreads();

        {   // q@G + LIF: wave w owns rows [(w*196)>>4, ((w+1)*196)>>4)
            const int rbeg = (w * 196) >> 4;
            const int rend = ((w + 1) * 196) >> 4;
            int r = rbeg;
            for (; r + 1 < rend; r += 2) {
                const ull q0 = qrow[r], q1 = qrow[r + 1];
                const uint a0 = (uint)q0, a1 = (uint)(q0 >> 32);
                const uint b0 = (uint)q1, b1 = (uint)(q1 >> 32);
                uint s0 = 0, s1 = 0;
#pragma unroll
                for (int d = 0; d < 32; ++d) {
                    const uint g = G[d][lane];
                    s0 += ((a0 >> d) & 1u) * g;
                    s1 += ((b0 >> d) & 1u) * g;
                }
#pragma unroll
                for (int d = 0; d < 32; ++d) {
                    const uint g = G[32 + d][lane];
                    s0 += ((a1 >> d) & 1u) * g;
                    s1 += ((b1 >> d) & 1u) * g;
                }
                const float y0 = (float)s0 * 0.125f;
                const float v0 = t ? vstate[r][lane] : 0.0f;
                const float h0 = __fadd_rn(v0, __fmul_rn(__fsub_rn(y0, v0), sg));
                const bool sp0 = h0 >= 1.0f;
                vstate[r][lane] = sp0 ? 0.0f : h0;
                const ull m0 = __ballot(sp0);
                const float y1 = (float)s1 * 0.125f;
                const float v1 = t ? vstate[r + 1][lane] : 0.0f;
                const float h1 = __fadd_rn(v1, __fmul_rn(__fsub_rn(y1, v1), sg));
                const bool sp1 = h1 >= 1.0f;
                vstate[r + 1][lane] = sp1 ? 0.0f : h1;
                const ull m1 = __ballot(sp1);
                if (lane == 0) { sbm[r] = m0; sbm[r + 1] = m1; }
            }
            if (r < rend) {   // odd-size tail
                const ull q0 = qrow[r];
                const uint a0 = (uint)q0, a1 = (uint)(q0 >> 32);
                uint s0 = 0;
#pragma unroll
                for (int d = 0; d < 32; ++d) s0 += ((a0 >> d) & 1u) * (uint)G[d][lane];
#pragma unroll
                for (int d = 0; d < 32; ++d) s0 += ((a1 >> d) & 1u) * (uint)G[32 + d][lane];
                const float y0 = (float)s0 * 0.125f;
                const float v0 = t ? vstate[r][lane] : 0.0f;
                const float h0 = __fadd_rn(v0, __fmul_rn(__fsub_rn(y0, v0), sg));
                const bool sp0 = h0 >= 1.0f;
                vstate[r][lane] = sp0 ? 0.0f : h0;
                const ull m0 = __ballot(sp0);
                if (lane == 0) sbm[r] = m0;
            }
        }
        __syncthreads();

        // Pack spikes into proj k-order words (e changes at most once/word).
        {
            uint* Yw = Ym + (size_t)tb * 3136 + h * 392;
            for (int wd = tid; wd < 392; wd += 1024) {
                const int fb = wd * 32;
                const int e0 = fb / 196;
                const int r0 = fb - e0 * 196;
                const int run = (196 - r0 >= 32) ? 32 : (196 - r0);
                uint word = 0;
                for (int j = 0; j < run; ++j)
                    word |= (uint)((sbm[r0 + j] >> e0) & 1ull) << j;
                for (int j = run; j < 32; ++j)
                    word |= (uint)((sbm[j - run] >> (e0 + 1)) & 1ull) << j;
                Yw[wd] = word;
            }
        }
        __syncthreads();
    }
}

// ---------------------------------------------------------------------------
// Workspace (160,563,200 B):
//   u0/u1/u2 : fp32 [128][196][512] 51,380,224 B each
//   Qm/Km/Vm : [128][8][196] ull, 1,605,632 B each
//   Ym       : [128][3136] uint, 1,605,632 B
// Aliases: proj-u = u0 (dead after lif_mask3).
// ---------------------------------------------------------------------------
extern "C" void kernel_launch(void* const* d_in, const int* in_sizes, int n_in,
                              void* d_out, int out_size, void* d_ws, size_t ws_size,
                              hipStream_t stream) {
    const float* x  = (const float*)d_in[0];
    const float* Wq = (const float*)d_in[1];
    const float* Wk = (const float*)d_in[2];
    const float* Wv = (const float*)d_in[3];
    const float* Wp = (const float*)d_in[4];
    const float* bp = (const float*)d_in[5];
    const float* wq = (const float*)d_in[6];
    const float* wk = (const float*)d_in[7];
    const float* wv = (const float*)d_in[8];
    const float* wa = (const float*)d_in[9];
    const float* wp = (const float*)d_in[10];
    float* out = (float*)d_out;

    char* ws = (char*)d_ws;
    float* u0 = (float*)ws;
    float* u1 = (float*)(ws + (size_t)51380224);
    float* u2 = (float*)(ws + (size_t)2 * 51380224);
    ull* Qm   = (ull*)(ws + (size_t)3 * 51380224);
    ull* Km   = Qm + 200704;
    ull* Vm   = Km + 200704;
    uint* Ym  = (uint*)(ws + (size_t)3 * 51380224 + (size_t)3 * 1605632);
    float* up = u0;    // proj GEMM output aliases u0

    // Q/K/V GEMMs: 16x8 microtile, waves_per_eu(2,2)-pinned, 1176 blocks
    gemm_wpe<3, false><<<1176, 256, 0, stream>>>(x, Wq, Wk, Wv, nullptr,
                                                 u0, u1, u2);
    // LIF -> spike bitmasks
    lif_mask3<<<1176, 256, 0, stream>>>(u0, u1, u2, wq, wk, wv, Qm);

    // Attention + attn_lif -> packed spike words (1024 threads)
    attn_fused<<<256, 1024, 0, stream>>>(Qm, Km, Vm, wa, Ym);

    // Projection + bias from bitmask A (64x128 tiles, 1568 blocks)
    gemm_mask<<<1568, 256, 0, stream>>>(Ym, Wp, bp, up);

    // proj LIF -> output spikes
    lif_out<<<392, 256, 0, stream>>>(up, wp, out);
}

// Round 15
// 819.006 us; speedup vs baseline: 1.4962x; 1.4962x over previous
//
#include <hip/hip_runtime.h>

#define NC 100352       // N*C = 196*512
typedef unsigned long long ull;

// ---------------------------------------------------------------------------
// QKV GEMM: round-8/11/12 body (validated 3x at 490 us @ 68% VALU, VGPR 72).
// 128x128 tile, BK=16, 256 threads, 8x8 microtile split 4+4 at +64,
// single-buffered LDS, 2 barriers/BK. k-ascending sequential fmaf ->
// bit-identical (absmax 0.0, rounds 1-14). NMAT=3 packs Q/K/V, 2352 blocks,
// XCD-bijective swizzle. AT its structural cap: per CU-k, LDS delivery
// 16 b128 x 12cy = 192 cy vs 128 VALU-cy -> 67% ceiling, 68% measured.
// 16x8/12x8 fat tiles: dead (5 attempts; allocator clamps at 128 VGPR).
// ---------------------------------------------------------------------------
template <int NMAT, bool BIAS>
__global__ __launch_bounds__(256) void gemm_nt(
    const float* __restrict__ A,
    const float* __restrict__ W0, const float* __restrict__ W1,
    const float* __restrict__ W2, const float* __restrict__ bias,
    float* __restrict__ C0, float* __restrict__ C1, float* __restrict__ C2)
{
    __shared__ float As[16][132];
    __shared__ float Bs[16][132];

    const int chunk = (NMAT * 784) >> 3;
    const int w = ((int)blockIdx.x & 7) * chunk + ((int)blockIdx.x >> 3);
    const int rp = w / (4 * NMAT);                 // row panel 0..195
    const int rem = w - rp * (4 * NMAT);
    const int br = rem >> 2;
    const int cb = rem & 3;

    const float* Wb = (NMAT == 1 || br == 0) ? W0 : (br == 1 ? W1 : W2);
    float* Cb = (NMAT == 1 || br == 0) ? C0 : (br == 1 ? C1 : C2);

    const int tid = threadIdx.x;
    const int r0 = tid >> 2;          // 0..63 load row (and +64)
    const int kq = (tid & 3) << 2;    // 0,4,8,12 k-offset for float4 load
    const int rg = (tid >> 4) << 2;   // compute row base
    const int cg = (tid & 15) << 2;   // compute col base

    float acc[8][8] = {};
    const float* A0 = A + (size_t)(rp * 128 + r0) * 512 + kq;
    const float* A1 = A0 + (size_t)64 * 512;
    const float* B0 = Wb + (size_t)(cb * 128 + r0) * 512 + kq;
    const float* B1 = B0 + (size_t)64 * 512;

    for (int k0 = 0; k0 < 512; k0 += 16) {
        const float4 a0 = *(const float4*)(A0 + k0);
        const float4 a1 = *(const float4*)(A1 + k0);
        const float4 b0 = *(const float4*)(B0 + k0);
        const float4 b1 = *(const float4*)(B1 + k0);
        __syncthreads();  // previous iteration's LDS reads done
        As[kq + 0][r0] = a0.x; As[kq + 1][r0] = a0.y; As[kq + 2][r0] = a0.z; As[kq + 3][r0] = a0.w;
        As[kq + 0][r0 + 64] = a1.x; As[kq + 1][r0 + 64] = a1.y; As[kq + 2][r0 + 64] = a1.z; As[kq + 3][r0 + 64] = a1.w;
        Bs[kq + 0][r0] = b0.x; Bs[kq + 1][r0] = b0.y; Bs[kq + 2][r0] = b0.z; Bs[kq + 3][r0] = b0.w;
        Bs[kq + 0][r0 + 64] = b1.x; Bs[kq + 1][r0 + 64] = b1.y; Bs[kq + 2][r0 + 64] = b1.z; Bs[kq + 3][r0 + 64] = b1.w;
        __syncthreads();
#pragma unroll
        for (int k = 0; k < 16; ++k) {
            float av[8], bv[8];
            *(float4*)&av[0] = *(const float4*)&As[k][rg];
            *(float4*)&av[4] = *(const float4*)&As[k][rg + 64];
            *(float4*)&bv[0] = *(const float4*)&Bs[k][cg];
            *(float4*)&bv[4] = *(const float4*)&Bs[k][cg + 64];
#pragma unroll
            for (int i = 0; i < 8; ++i)
#pragma unroll
                for (int j = 0; j < 8; ++j)
                    acc[i][j] = fmaf(av[i], bv[j], acc[i][j]);
        }
    }

#pragma unroll
    for (int ih = 0; ih < 2; ++ih)
#pragma unroll
        for (int i = 0; i < 4; ++i) {
            const int row = rp * 128 + rg + i + ih * 64;
#pragma unroll
            for (int jh = 0; jh < 2; ++jh) {
                const int col = cb * 128 + cg + jh * 64;
                float4 o;
                o.x = acc[ih * 4 + i][jh * 4 + 0];
                o.y = acc[ih * 4 + i][jh * 4 + 1];
                o.z = acc[ih * 4 + i][jh * 4 + 2];
                o.w = acc[ih * 4 + i][jh * 4 + 3];
                if (BIAS) {
                    o.x += bias[col + 0]; o.y += bias[col + 1];
                    o.z += bias[col + 2]; o.w += bias[col + 3];
                }
                *(float4*)&Cb[(size_t)row * 512 + col] = o;
            }
        }
}

// ---------------------------------------------------------------------------
// proj GEMM with bitmask A (validated rounds 12-14): 64x128 tile, 1568 blocks.
// ---------------------------------------------------------------------------
__global__ __launch_bounds__(256) void gemm_mask(
    const uint* __restrict__ Am,
    const float* __restrict__ W, const float* __restrict__ bias,
    float* __restrict__ C)
{
    __shared__ float Bs[16][132];

    const int w = ((int)blockIdx.x & 7) * 196 + ((int)blockIdx.x >> 3);
    const int rp = w >> 2;            // 0..391 (64-row panels)
    const int cb = w & 3;

    const int tid = threadIdx.x;
    const int r0 = tid >> 2;
    const int kq = (tid & 3) << 2;
    const int rg = (tid >> 4) << 2;   // 0..60 : 4 rows of 64
    const int cg = (tid & 15) << 2;   // 0..60 : cols cg / cg+64

    const float* B0 = W + (size_t)(cb * 128 + r0) * 512 + kq;
    const float* B1 = B0 + (size_t)64 * 512;

    const uint* mp[4];
#pragma unroll
    for (int i = 0; i < 4; ++i) {
        const int row = rp * 64 + rg + i;
        const int tb = row / 196;
        const int n = row - tb * 196;
        mp[i] = Am + (size_t)tb * 3136 + n * 16;
    }

    float acc[4][8] = {};

    for (int k0 = 0; k0 < 512; k0 += 16) {
        const float4 b0 = *(const float4*)(B0 + k0);
        const float4 b1 = *(const float4*)(B1 + k0);
        uint wv[4];
        const int wi = k0 >> 5;
        const int sh = k0 & 16;
#pragma unroll
        for (int m = 0; m < 4; ++m) wv[m] = mp[m][wi] >> sh;  // low 16 bits
        __syncthreads();
        Bs[kq + 0][r0] = b0.x; Bs[kq + 1][r0] = b0.y;
        Bs[kq + 2][r0] = b0.z; Bs[kq + 3][r0] = b0.w;
        Bs[kq + 0][r0 + 64] = b1.x; Bs[kq + 1][r0 + 64] = b1.y;
        Bs[kq + 2][r0 + 64] = b1.z; Bs[kq + 3][r0 + 64] = b1.w;
        __syncthreads();
#pragma unroll
        for (int k = 0; k < 16; ++k) {
            float bv[8], av[4];
            *(float4*)&bv[0] = *(const float4*)&Bs[k][cg];
            *(float4*)&bv[4] = *(const float4*)&Bs[k][cg + 64];
#pragma unroll
            for (int m = 0; m < 4; ++m)
                av[m] = ((wv[m] >> k) & 1u) ? 1.0f : 0.0f;
#pragma unroll
            for (int i = 0; i < 4; ++i)
#pragma unroll
                for (int j = 0; j < 8; ++j)
                    acc[i][j] = fmaf(av[i], bv[j], acc[i][j]);
        }
    }

#pragma unroll
    for (int i = 0; i < 4; ++i) {
        const int row = rp * 64 + rg + i;
#pragma unroll
        for (int jh = 0; jh < 2; ++jh) {
            const int col = cb * 128 + cg + jh * 64;
            float4 o;
            o.x = acc[i][jh * 4 + 0] + bias[col + 0];
            o.y = acc[i][jh * 4 + 1] + bias[col + 1];
            o.z = acc[i][jh * 4 + 2] + bias[col + 2];
            o.w = acc[i][jh * 4 + 3] + bias[col + 3];
            *(float4*)&C[(size_t)row * 512 + col] = o;
        }
    }
}

// ---------------------------------------------------------------------------
// LIF over 128 steps for Q/K/V, emitting bitmasks (4-step load MLP).
// ---------------------------------------------------------------------------
__global__ __launch_bounds__(256) void lif_mask3(
    const float* __restrict__ U0, const float* __restrict__ U1,
    const float* __restrict__ U2,
    const float* __restrict__ wq, const float* __restrict__ wk,
    const float* __restrict__ wv, ull* __restrict__ M)
{
    const int br = blockIdx.x / 392;
    const int blk = blockIdx.x - br * 392;
    const int i = blk * 256 + threadIdx.x;
    const float* U = (br == 0) ? U0 : (br == 1 ? U1 : U2);
    const float wv_ = (br == 0) ? wq[0] : (br == 1 ? wk[0] : wv[0]);
    const float sg = 1.0f / (1.0f + expf(-wv_));
    const bool l0 = (threadIdx.x & 63) == 0;
    ull* Mw = M + (size_t)br * 200704 + ((i >> 6) & 7) * 196 + (i >> 9);
    float v = 0.0f;
    for (int t0 = 0; t0 < 128; t0 += 4) {
        float x[4];
#pragma unroll
        for (int j = 0; j < 4; ++j) x[j] = U[(size_t)(t0 + j) * NC + i];
#pragma unroll
        for (int j = 0; j < 4; ++j) {
            const float h = __fadd_rn(v, __fmul_rn(__fsub_rn(x[j], v), sg));
            const bool sp = (h >= 1.0f);
            const ull m = __ballot(sp);
            if (l0) Mw[(size_t)(t0 + j) * 1568] = m;
            v = sp ? 0.0f : h;
        }
    }
}

// ---------------------------------------------------------------------------
// proj LIF: float spikes out (4-step load MLP).
// ---------------------------------------------------------------------------
__global__ __launch_bounds__(256) void lif_out(const float* __restrict__ U,
                                               const float* __restrict__ wp,
                                               float* __restrict__ out)
{
    const int i = blockIdx.x * 256 + threadIdx.x;
    const float sg = 1.0f / (1.0f + expf(-wp[0]));
    float v = 0.0f;
    for (int t0 = 0; t0 < 128; t0 += 4) {
        float x[4];
#pragma unroll
        for (int j = 0; j < 4; ++j) x[j] = U[(size_t)(t0 + j) * NC + i];
#pragma unroll
        for (int j = 0; j < 4; ++j) {
            const float h = __fadd_rn(v, __fmul_rn(__fsub_rn(x[j], v), sg));
            const bool sp = (h >= 1.0f);
            out[(size_t)(t0 + j) * NC + i] = sp ? 1.0f : 0.0f;
            v = sp ? 0.0f : h;
        }
    }
}

// ---------------------------------------------------------------------------
// Fused attention + attn_lif, 1024 threads (validated rounds 13/14).
// ---------------------------------------------------------------------------
__global__ __launch_bounds__(1024) void attn_fused(const ull* __restrict__ Qm,
                                                   const ull* __restrict__ Km,
                                                   const ull* __restrict__ Vm,
                                                   const float* __restrict__ wa,
                                                   uint* __restrict__ Ym)
{
    const int b = blockIdx.x >> 3;
    const int h = blockIdx.x & 7;
    const int tid = threadIdx.x;
    const int w = tid >> 6;          // 0..15
    const int lane = tid & 63;

    __shared__ ull qrow[256], krow[256], vrow[256];
    __shared__ uint kcol32[64][4][2], vcol32[64][4][2];
    __shared__ ushort G[64][64];
    __shared__ float vstate[196][64];
    __shared__ ull sbm[208];

    const float sg = 1.0f / (1.0f + expf(-wa[0]));

    for (int t = 0; t < 4; ++t) {
        const int tb = t * 32 + b;
        const size_t mb = (size_t)tb * 1568 + (size_t)h * 196;
        if (tid < 196) {
            qrow[tid] = Qm[mb + tid];
            krow[tid] = Km[mb + tid];
            vrow[tid] = Vm[mb + tid];
        } else if (tid < 256) {
            qrow[tid] = 0; krow[tid] = 0; vrow[tid] = 0;
        }
        __syncthreads();

        if (w < 8) {  // transpose: wave w -> (j = w>>1, half = w&1)
            const int j = w >> 1, half = w & 1;
            const int base = j * 64 + half * 32;
            uint kc = 0, vc = 0;
#pragma unroll 8
            for (int m = 0; m < 32; ++m) {
                kc |= (uint)((krow[base + m] >> lane) & 1ull) << m;
                vc |= (uint)((vrow[base + m] >> lane) & 1ull) << m;
            }
            kcol32[lane][j][half] = kc; vcol32[lane][j][half] = vc;
        }
        __syncthreads();

        for (int p = tid; p < 4096; p += 1024) {
            const int d1 = p >> 6, d2 = p & 63;
            int g = 0;
#pragma unroll
            for (int j = 0; j < 4; ++j)
                g += __popc(kcol32[d1][j][0] & vcol32[d2][j][0]) +
                     __popc(kcol32[d1][j][1] & vcol32[d2][j][1]);
            G[d1][d2] = (ushort)g;
        }
        __syncthreads();

        {   // q@G + LIF: wave w owns rows [(w*196)>>4, ((w+1)*196)>>4)
            const int rbeg = (w * 196) >> 4;
            const int rend = ((w + 1) * 196) >> 4;
            int r = rbeg;
            for (; r + 1 < rend; r += 2) {
                const ull q0 = qrow[r], q1 = qrow[r + 1];
                const uint a0 = (uint)q0, a1 = (uint)(q0 >> 32);
                const uint b0 = (uint)q1, b1 = (uint)(q1 >> 32);
                uint s0 = 0, s1 = 0;
#pragma unroll
                for (int d = 0; d < 32; ++d) {
                    const uint g = G[d][lane];
                    s0 += ((a0 >> d) & 1u) * g;
                    s1 += ((b0 >> d) & 1u) * g;
                }
#pragma unroll
                for (int d = 0; d < 32; ++d) {
                    const uint g = G[32 + d][lane];
                    s0 += ((a1 >> d) & 1u) * g;
                    s1 += ((b1 >> d) & 1u) * g;
                }
                const float y0 = (float)s0 * 0.125f;
                const float v0 = t ? vstate[r][lane] : 0.0f;
                const float h0 = __fadd_rn(v0, __fmul_rn(__fsub_rn(y0, v0), sg));
                const bool sp0 = h0 >= 1.0f;
                vstate[r][lane] = sp0 ? 0.0f : h0;
                const ull m0 = __ballot(sp0);
                const float y1 = (float)s1 * 0.125f;
                const float v1 = t ? vstate[r + 1][lane] : 0.0f;
                const float h1 = __fadd_rn(v1, __fmul_rn(__fsub_rn(y1, v1), sg));
                const bool sp1 = h1 >= 1.0f;
                vstate[r + 1][lane] = sp1 ? 0.0f : h1;
                const ull m1 = __ballot(sp1);
                if (lane == 0) { sbm[r] = m0; sbm[r + 1] = m1; }
            }
            if (r < rend) {   // odd-size tail
                const ull q0 = qrow[r];
                const uint a0 = (uint)q0, a1 = (uint)(q0 >> 32);
                uint s0 = 0;
#pragma unroll
                for (int d = 0; d < 32; ++d) s0 += ((a0 >> d) & 1u) * (uint)G[d][lane];
#pragma unroll
                for (int d = 0; d < 32; ++d) s0 += ((a1 >> d) & 1u) * (uint)G[32 + d][lane];
                const float y0 = (float)s0 * 0.125f;
                const float v0 = t ? vstate[r][lane] : 0.0f;
                const float h0 = __fadd_rn(v0, __fmul_rn(__fsub_rn(y0, v0), sg));
                const bool sp0 = h0 >= 1.0f;
                vstate[r][lane] = sp0 ? 0.0f : h0;
                const ull m0 = __ballot(sp0);
                if (lane == 0) sbm[r] = m0;
            }
        }
        __syncthreads();

        // Pack spikes into proj k-order words (e changes at most once/word).
        {
            uint* Yw = Ym + (size_t)tb * 3136 + h * 392;
            for (int wd = tid; wd < 392; wd += 1024) {
                const int fb = wd * 32;
                const int e0 = fb / 196;
                const int r0 = fb - e0 * 196;
                const int run = (196 - r0 >= 32) ? 32 : (196 - r0);
                uint word = 0;
                for (int j = 0; j < run; ++j)
                    word |= (uint)((sbm[r0 + j] >> e0) & 1ull) << j;
                for (int j = run; j < 32; ++j)
                    word |= (uint)((sbm[j - run] >> (e0 + 1)) & 1ull) << j;
                Yw[wd] = word;
            }
        }
        __syncthreads();
    }
}

// ---------------------------------------------------------------------------
// Workspace (160,563,200 B):
//   u0/u1/u2 : fp32 [128][196][512] 51,380,224 B each
//   Qm/Km/Vm : [128][8][196] ull, 1,605,632 B each
//   Ym       : [128][3136] uint, 1,605,632 B
// Aliases: proj-u = u0 (dead after lif_mask3).
// ---------------------------------------------------------------------------
extern "C" void kernel_launch(void* const* d_in, const int* in_sizes, int n_in,
                              void* d_out, int out_size, void* d_ws, size_t ws_size,
                              hipStream_t stream) {
    const float* x  = (const float*)d_in[0];
    const float* Wq = (const float*)d_in[1];
    const float* Wk = (const float*)d_in[2];
    const float* Wv = (const float*)d_in[3];
    const float* Wp = (const float*)d_in[4];
    const float* bp = (const float*)d_in[5];
    const float* wq = (const float*)d_in[6];
    const float* wk = (const float*)d_in[7];
    const float* wv = (const float*)d_in[8];
    const float* wa = (const float*)d_in[9];
    const float* wp = (const float*)d_in[10];
    float* out = (float*)d_out;

    char* ws = (char*)d_ws;
    float* u0 = (float*)ws;
    float* u1 = (float*)(ws + (size_t)51380224);
    float* u2 = (float*)(ws + (size_t)2 * 51380224);
    ull* Qm   = (ull*)(ws + (size_t)3 * 51380224);
    ull* Km   = Qm + 200704;
    ull* Vm   = Km + 200704;
    uint* Ym  = (uint*)(ws + (size_t)3 * 51380224 + (size_t)3 * 1605632);
    float* up = u0;    // proj GEMM output aliases u0

    // Q/K/V GEMMs: validated 8x8 body, one merged 2352-block dispatch
    gemm_nt<3, false><<<2352, 256, 0, stream>>>(x, Wq, Wk, Wv, nullptr,
                                                u0, u1, u2);
    // LIF -> spike bitmasks
    lif_mask3<<<1176, 256, 0, stream>>>(u0, u1, u2, wq, wk, wv, Qm);

    // Attention + attn_lif -> packed spike words (1024 threads)
    attn_fused<<<256, 1024, 0, stream>>>(Qm, Km, Vm, wa, Ym);

    // Projection + bias from bitmask A (64x128 tiles, 1568 blocks)
    gemm_mask<<<1568, 256, 0, stream>>>(Ym, Wp, bp, up);

    // proj LIF -> output spikes
    lif_out<<<392, 256, 0, stream>>>(up, wp, out);
}